// Round 2
// baseline (1637.242 us; speedup 1.0000x reference)
//
#include <hip/hip_runtime.h>
#include <cstddef>

#define BB 4
#define LL 2048
#define DD 1024
#define HH 16
#define HDIM 64
#define NROW (BB * LL)   // 8192

typedef __attribute__((ext_vector_type(8))) short bf16x8;
typedef __attribute__((ext_vector_type(4))) float f32x4;

__device__ __forceinline__ unsigned short f2bf(float f) {
    unsigned int u = __float_as_uint(f);
    u += 0x7FFFu + ((u >> 16) & 1u);   // round-to-nearest-even
    return (unsigned short)(u >> 16);
}

// ---------------------------------------------------------------------------
// Elementwise f32 -> bf16 (x_q, x_kv)
// ---------------------------------------------------------------------------
__global__ __launch_bounds__(256) void cvt_f32_bf16(
    const float* __restrict__ in, unsigned short* __restrict__ out, int n)
{
    int i = (blockIdx.x * 256 + threadIdx.x) * 4;
    if (i < n) {
        float4 v = *(const float4*)(in + i);
        ushort4 o;
        o.x = f2bf(v.x); o.y = f2bf(v.y); o.z = f2bf(v.z); o.w = f2bf(v.w);
        *(ushort4*)(out + i) = o;
    }
}

// ---------------------------------------------------------------------------
// W [K][N] f32  ->  Wt [N][K] bf16   (so GEMM B-fragments are K-contiguous)
// ---------------------------------------------------------------------------
__global__ __launch_bounds__(256) void cvt_transpose_w(
    const float* __restrict__ W, unsigned short* __restrict__ Wt, int K, int N)
{
    __shared__ float Ls[32][33];
    const int k0 = blockIdx.y * 32, n0 = blockIdx.x * 32;
    const int t = threadIdx.x;
    const int r = t >> 3, c = (t & 7) * 4;
    float4 v = *(const float4*)(W + (size_t)(k0 + r) * N + n0 + c);
    Ls[r][c + 0] = v.x; Ls[r][c + 1] = v.y; Ls[r][c + 2] = v.z; Ls[r][c + 3] = v.w;
    __syncthreads();
    ushort4 o;
    o.x = f2bf(Ls[c + 0][r]); o.y = f2bf(Ls[c + 1][r]);
    o.z = f2bf(Ls[c + 2][r]); o.w = f2bf(Ls[c + 3][r]);
    *(ushort4*)(Wt + (size_t)(n0 + r) * K + k0 + c) = o;
}

// ---------------------------------------------------------------------------
// Extract V half of KVb and transpose per head: Vt[bh][d(64)][k(2048)] bf16
// ---------------------------------------------------------------------------
__global__ __launch_bounds__(256) void transpose_v(
    const unsigned short* __restrict__ KVb, unsigned short* __restrict__ Vt)
{
    __shared__ unsigned short Ls[64][68];   // [k][d], pad 68 -> 8B-aligned rows
    const int k0 = blockIdx.x * 64, bh = blockIdx.y;
    const int b = bh >> 4, h = bh & 15;
    const int t = threadIdx.x;
    #pragma unroll
    for (int p = 0; p < 2; ++p) {
        int idx = t + 256 * p, r = idx >> 3, u = idx & 7;
        const unsigned short* src =
            KVb + (size_t)(b * LL + k0 + r) * 2048 + 1024 + h * HDIM + u * 8;
        ushort4 a = *(const ushort4*)src;
        ushort4 c = *(const ushort4*)(src + 4);
        *(ushort4*)&Ls[r][u * 8] = a;
        *(ushort4*)&Ls[r][u * 8 + 4] = c;
    }
    __syncthreads();
    #pragma unroll
    for (int p = 0; p < 2; ++p) {
        int idx = t + 256 * p, rd = idx >> 3, u = idx & 7;   // rd = d, u*8 = k
        ushort4 a, c;
        a.x = Ls[u * 8 + 0][rd]; a.y = Ls[u * 8 + 1][rd];
        a.z = Ls[u * 8 + 2][rd]; a.w = Ls[u * 8 + 3][rd];
        c.x = Ls[u * 8 + 4][rd]; c.y = Ls[u * 8 + 5][rd];
        c.z = Ls[u * 8 + 6][rd]; c.w = Ls[u * 8 + 7][rd];
        unsigned short* dst = Vt + ((size_t)bh * HDIM + rd) * LL + k0 + u * 8;
        *(ushort4*)dst = a;
        *(ushort4*)(dst + 4) = c;
    }
}

// ---------------------------------------------------------------------------
// C[M,N] = A[M,K] @ Bt[N,K]^T + bias ; A,Bt bf16, acc fp32.
// 128x128 tile, BK=64, 4 waves (2x2), wave tile 64x64 = 4x4 MFMA 16x16x32.
// LDS rows are 128B with XOR-unit swizzle: byte-unit u' = u ^ (row&7)
// -> all ds_read_b128 are <=2-way bank aliased (free).
// ---------------------------------------------------------------------------
template <bool BF16OUT>
__global__ __launch_bounds__(256) void gemm_bf16(
    int K, int N,
    const unsigned short* __restrict__ A,
    const unsigned short* __restrict__ Bt,
    const float* __restrict__ bias,
    void* __restrict__ Cout)
{
    __shared__ __align__(16) unsigned short As[128 * 64];
    __shared__ __align__(16) unsigned short Bs[128 * 64];
    const int t = threadIdx.x, lane = t & 63, w = t >> 6;
    const int lhi = lane >> 4, llo = lane & 15;
    const int wm = w >> 1, wn = w & 1;
    const int row0 = blockIdx.y * 128, col0 = blockIdx.x * 128;

    f32x4 acc[4][4];
    #pragma unroll
    for (int mi = 0; mi < 4; ++mi)
        #pragma unroll
        for (int ni = 0; ni < 4; ++ni) acc[mi][ni] = (f32x4){0.f, 0.f, 0.f, 0.f};

    const int nkt = K >> 6;
    for (int kt = 0; kt < nkt; ++kt) {
        __syncthreads();
        #pragma unroll
        for (int p = 0; p < 4; ++p) {
            int idx = t + 256 * p, r = idx >> 3, u = idx & 7;
            bf16x8 av = *(const bf16x8*)(A + (size_t)(row0 + r) * K + kt * 64 + u * 8);
            *(bf16x8*)&As[r * 64 + ((u ^ (r & 7)) * 8)] = av;
            bf16x8 bv = *(const bf16x8*)(Bt + (size_t)(col0 + r) * K + kt * 64 + u * 8);
            *(bf16x8*)&Bs[r * 64 + ((u ^ (r & 7)) * 8)] = bv;
        }
        __syncthreads();
        #pragma unroll
        for (int ks = 0; ks < 2; ++ks) {
            bf16x8 af[4], bfr[4];
            #pragma unroll
            for (int mi = 0; mi < 4; ++mi) {
                int r = 64 * wm + 16 * mi + llo;
                int u = ks * 4 + lhi;
                af[mi] = *(const bf16x8*)&As[r * 64 + ((u ^ (r & 7)) * 8)];
            }
            #pragma unroll
            for (int ni = 0; ni < 4; ++ni) {
                int r = 64 * wn + 16 * ni + llo;
                int u = ks * 4 + lhi;
                bfr[ni] = *(const bf16x8*)&Bs[r * 64 + ((u ^ (r & 7)) * 8)];
            }
            #pragma unroll
            for (int mi = 0; mi < 4; ++mi)
                #pragma unroll
                for (int ni = 0; ni < 4; ++ni)
                    acc[mi][ni] = __builtin_amdgcn_mfma_f32_16x16x32_bf16(
                        af[mi], bfr[ni], acc[mi][ni], 0, 0, 0);
        }
    }
    #pragma unroll
    for (int mi = 0; mi < 4; ++mi) {
        #pragma unroll
        for (int i = 0; i < 4; ++i) {
            int row = row0 + 64 * wm + 16 * mi + 4 * lhi + i;
            #pragma unroll
            for (int ni = 0; ni < 4; ++ni) {
                int col = col0 + 64 * wn + 16 * ni + llo;
                float v = acc[mi][ni][i] + bias[col];
                if (BF16OUT)
                    ((unsigned short*)Cout)[(size_t)row * N + col] = f2bf(v);
                else
                    ((float*)Cout)[(size_t)row * N + col] = v;
            }
        }
    }
}

// ---------------------------------------------------------------------------
// Fused attention. Block = (q-tile of 64 rows, bh). 4 waves, wave = 16 q-rows.
// Phase 1: online (max, sumexp) stats over all k-tiles (QK^T MFMA only).
// Phase 2: recompute scores (bitwise identical), P = exp(s-m)/l, write P to
//          attn output (fp32, coalesced), stage P->LDS bf16, PV MFMA into regs.
// ---------------------------------------------------------------------------
__global__ __launch_bounds__(256) void attn_fused(
    const unsigned short* __restrict__ Qb,    // [NROW][1024]
    const unsigned short* __restrict__ KVb,   // [NROW][2048] (K = cols 0..1023)
    const unsigned short* __restrict__ Vt,    // [64][64][2048]
    float* __restrict__ attn,                 // [64][2048][2048]
    unsigned short* __restrict__ ctxb)        // [NROW][1024]
{
    __shared__ __align__(16) unsigned short Qs[64 * 64];
    __shared__ __align__(16) unsigned short Ks[64 * 64];
    __shared__ __align__(16) unsigned short Vs[64 * 64];
    __shared__ __align__(16) unsigned short Ps[4][16 * 64];
    const int qt = blockIdx.x, bh = blockIdx.y;
    const int b = bh >> 4, h = bh & 15;
    const int t = threadIdx.x, lane = t & 63, w = t >> 6;
    const int lhi = lane >> 4, llo = lane & 15;
    const float scale = 0.125f;

    // stage Q tile (swizzled rows of 128B)
    #pragma unroll
    for (int p = 0; p < 2; ++p) {
        int idx = t + 256 * p, r = idx >> 3, u = idx & 7;
        bf16x8 v = *(const bf16x8*)(Qb + (size_t)(b * LL + qt * 64 + r) * DD + h * HDIM + u * 8);
        *(bf16x8*)&Qs[r * 64 + ((u ^ (r & 7)) * 8)] = v;
    }
    __syncthreads();
    bf16x8 qf[2];
    {
        int r = 16 * w + llo;
        #pragma unroll
        for (int ks = 0; ks < 2; ++ks) {
            int u = ks * 4 + lhi;
            qf[ks] = *(const bf16x8*)&Qs[r * 64 + ((u ^ (r & 7)) * 8)];
        }
    }

    float m[4], l[4];
    #pragma unroll
    for (int i = 0; i < 4; ++i) { m[i] = -1e30f; l[i] = 0.f; }

    // ---------------- phase 1: stats ----------------
    for (int kt = 0; kt < 32; ++kt) {
        __syncthreads();
        #pragma unroll
        for (int p = 0; p < 2; ++p) {
            int idx = t + 256 * p, r = idx >> 3, u = idx & 7;
            bf16x8 v = *(const bf16x8*)(KVb + (size_t)(b * LL + kt * 64 + r) * 2048 + h * HDIM + u * 8);
            *(bf16x8*)&Ks[r * 64 + ((u ^ (r & 7)) * 8)] = v;
        }
        __syncthreads();
        f32x4 acc[4];
        #pragma unroll
        for (int ni = 0; ni < 4; ++ni) acc[ni] = (f32x4){0.f, 0.f, 0.f, 0.f};
        #pragma unroll
        for (int ks = 0; ks < 2; ++ks)
            #pragma unroll
            for (int ni = 0; ni < 4; ++ni) {
                int r = 16 * ni + llo;
                int u = ks * 4 + lhi;
                bf16x8 kf = *(const bf16x8*)&Ks[r * 64 + ((u ^ (r & 7)) * 8)];
                acc[ni] = __builtin_amdgcn_mfma_f32_16x16x32_bf16(qf[ks], kf, acc[ni], 0, 0, 0);
            }
        #pragma unroll
        for (int i = 0; i < 4; ++i) {
            float tm = fmaxf(fmaxf(acc[0][i], acc[1][i]), fmaxf(acc[2][i], acc[3][i])) * scale;
            #pragma unroll
            for (int off = 1; off <= 8; off <<= 1) tm = fmaxf(tm, __shfl_xor(tm, off));
            float mn = fmaxf(m[i], tm);
            float ps = 0.f;
            #pragma unroll
            for (int ni = 0; ni < 4; ++ni) ps += __expf(acc[ni][i] * scale - mn);
            #pragma unroll
            for (int off = 1; off <= 8; off <<= 1) ps += __shfl_xor(ps, off);
            l[i] = l[i] * __expf(m[i] - mn) + ps;
            m[i] = mn;
        }
    }

    float invl[4];
    #pragma unroll
    for (int i = 0; i < 4; ++i) invl[i] = 1.f / l[i];

    f32x4 oacc[4];
    #pragma unroll
    for (int ni = 0; ni < 4; ++ni) oacc[ni] = (f32x4){0.f, 0.f, 0.f, 0.f};

    float* attn_base = attn + ((size_t)bh * LL + qt * 64) * LL;
    unsigned short* Pw = &Ps[w][0];

    // ---------------- phase 2: P write + PV ----------------
    for (int kt = 0; kt < 32; ++kt) {
        __syncthreads();
        #pragma unroll
        for (int p = 0; p < 2; ++p) {
            int idx = t + 256 * p, r = idx >> 3, u = idx & 7;
            bf16x8 kv = *(const bf16x8*)(KVb + (size_t)(b * LL + kt * 64 + r) * 2048 + h * HDIM + u * 8);
            *(bf16x8*)&Ks[r * 64 + ((u ^ (r & 7)) * 8)] = kv;
            bf16x8 vv = *(const bf16x8*)(Vt + ((size_t)bh * HDIM + r) * LL + kt * 64 + u * 8);
            *(bf16x8*)&Vs[r * 64 + ((u ^ (r & 7)) * 8)] = vv;
        }
        __syncthreads();
        f32x4 acc[4];
        #pragma unroll
        for (int ni = 0; ni < 4; ++ni) acc[ni] = (f32x4){0.f, 0.f, 0.f, 0.f};
        #pragma unroll
        for (int ks = 0; ks < 2; ++ks)
            #pragma unroll
            for (int ni = 0; ni < 4; ++ni) {
                int r = 16 * ni + llo;
                int u = ks * 4 + lhi;
                bf16x8 kf = *(const bf16x8*)&Ks[r * 64 + ((u ^ (r & 7)) * 8)];
                acc[ni] = __builtin_amdgcn_mfma_f32_16x16x32_bf16(qf[ks], kf, acc[ni], 0, 0, 0);
            }
        // P: write to global attn (coalesced 64B chunks) + stage bf16 to LDS
        #pragma unroll
        for (int ni = 0; ni < 4; ++ni)
            #pragma unroll
            for (int i = 0; i < 4; ++i) {
                int rq = 4 * lhi + i;          // q-row within wave tile
                int c = 16 * ni + llo;         // k-col within tile
                float pv = __expf(acc[ni][i] * scale - m[i]) * invl[i];
                attn_base[(size_t)(16 * w + rq) * LL + kt * 64 + c] = pv;
                int bu = c >> 3;
                Pw[rq * 64 + ((bu ^ (rq & 7)) * 8) + (c & 7)] = f2bf(pv);
            }
        // PV: ctx += P @ V   (same-wave LDS, compiler orders via lgkmcnt)
        #pragma unroll
        for (int ks = 0; ks < 2; ++ks) {
            int u = ks * 4 + lhi;
            int rp = llo;
            bf16x8 pf = *(const bf16x8*)&Pw[rp * 64 + ((u ^ (rp & 7)) * 8)];
            #pragma unroll
            for (int ni = 0; ni < 4; ++ni) {
                int rd = 16 * ni + llo;        // Vs row = d
                bf16x8 vf = *(const bf16x8*)&Vs[rd * 64 + ((u ^ (rd & 7)) * 8)];
                oacc[ni] = __builtin_amdgcn_mfma_f32_16x16x32_bf16(pf, vf, oacc[ni], 0, 0, 0);
            }
        }
    }
    // epilogue: ctx (bf16)
    #pragma unroll
    for (int ni = 0; ni < 4; ++ni)
        #pragma unroll
        for (int i = 0; i < 4; ++i) {
            int rq = 16 * w + 4 * lhi + i;
            int d = 16 * ni + llo;
            ctxb[(size_t)(b * LL + qt * 64 + rq) * DD + h * HDIM + d] = f2bf(oacc[ni][i]);
        }
}

extern "C" void kernel_launch(void* const* d_in, const int* in_sizes, int n_in,
                              void* d_out, int out_size, void* d_ws, size_t ws_size,
                              hipStream_t stream) {
    const float* x_q  = (const float*)d_in[0];
    const float* x_kv = (const float*)d_in[1];
    const float* Wq   = (const float*)d_in[2];
    const float* bq   = (const float*)d_in[3];
    const float* Wkv  = (const float*)d_in[4];
    const float* bkv  = (const float*)d_in[5];
    const float* Wo   = (const float*)d_in[6];
    const float* bo   = (const float*)d_in[7];

    float* out  = (float*)d_out;                       // [B,L,D] fp32
    float* attn = out + (size_t)NROW * DD;             // [B,H,L,L] fp32

    unsigned short* xqb  = (unsigned short*)d_ws;                  // 16MB
    unsigned short* xkvb = xqb  + (size_t)NROW * DD;               // 16MB
    unsigned short* Wqt  = xkvb + (size_t)NROW * DD;               // 2MB
    unsigned short* Wkvt = Wqt  + (size_t)DD * DD;                 // 4MB
    unsigned short* Wot  = Wkvt + (size_t)2 * DD * DD;             // 2MB
    unsigned short* Qb   = Wot  + (size_t)DD * DD;                 // 16MB
    unsigned short* KVb  = Qb   + (size_t)NROW * DD;               // 32MB
    unsigned short* Vtb  = KVb  + (size_t)NROW * 2 * DD;           // 16MB
    unsigned short* ctxb = Vtb  + (size_t)64 * HDIM * LL;          // 16MB  (total 120MB)

    dim3 blk(256);
    cvt_f32_bf16<<<NROW * DD / 1024, blk, 0, stream>>>(x_q, xqb, NROW * DD);
    cvt_f32_bf16<<<NROW * DD / 1024, blk, 0, stream>>>(x_kv, xkvb, NROW * DD);
    cvt_transpose_w<<<dim3(DD / 32, DD / 32), blk, 0, stream>>>(Wq, Wqt, DD, DD);
    cvt_transpose_w<<<dim3(2 * DD / 32, DD / 32), blk, 0, stream>>>(Wkv, Wkvt, DD, 2 * DD);
    cvt_transpose_w<<<dim3(DD / 32, DD / 32), blk, 0, stream>>>(Wo, Wot, DD, DD);

    gemm_bf16<true><<<dim3(DD / 128, NROW / 128), blk, 0, stream>>>(DD, DD, xqb, Wqt, bq, Qb);
    gemm_bf16<true><<<dim3(2 * DD / 128, NROW / 128), blk, 0, stream>>>(DD, 2 * DD, xkvb, Wkvt, bkv, KVb);
    transpose_v<<<dim3(LL / 64, 64), blk, 0, stream>>>(KVb, Vtb);
    attn_fused<<<dim3(LL / 64, 64), blk, 0, stream>>>(Qb, KVb, Vtb, attn, ctxb);
    gemm_bf16<false><<<dim3(DD / 128, NROW / 128), blk, 0, stream>>>(DD, DD, ctxb, Wot, bo, out);
}